// Round 2
// baseline (2069.287 us; speedup 1.0000x reference)
//
#include <hip/hip_runtime.h>

// ---------------------------------------------------------------------------
// RGAT-like layer on MI355X — round 4 (resubmit for measurement).
//   K0 : transpose+bf16-convert W2s/W2d -> Wt[512][128] (in ws)
//   K1 : MFMA feat GEMM: feat = gather(node_emb)@W + b  (bf16 in/out, fp32 acc)
//   K2 : histogram of edge_dst
//   K3 : exclusive scan (1 block)
//   K4 : scatter -> s64[pos] = (src<<27)|(edge_id<<5)|rtype, grouped by dst.
//        s64 ALIASES the x_out output region (E*8 == 25.6MB exactly); K6
//        fully overwrites x_out afterwards, so this is safe in-stream.
//   K5 : fused per-dst wave: pass1 logit->denominator only (NO stores, no
//        esrc/att scratch round-trip); pass2 recomputes logit from the fs row
//        already in registers, writes final normalized attention once,
//        computes softmax_D message, accumulates g in registers.
//   K6 : final SIMT GEMM -> x_out, emb_cat
// ---------------------------------------------------------------------------

#define NN_NODES 100000
#define NN_DST   50000
#define NBINS    50000

typedef short short8 __attribute__((ext_vector_type(8)));
typedef float f32x4  __attribute__((ext_vector_type(4)));

__device__ __forceinline__ float bflo(unsigned u){ return __uint_as_float(u << 16); }
__device__ __forceinline__ float bfhi(unsigned u){ return __uint_as_float(u & 0xFFFF0000u); }
__device__ __forceinline__ unsigned short f2bf(float f){
    unsigned u = __float_as_uint(f);
    unsigned r = (u + 0x7FFFu + ((u >> 16) & 1u)) >> 16;
    return (unsigned short)r;
}

// ---------------- K0: W[128][512] fp32 -> Wt[512][128] bf16 -----------------
__global__ __launch_bounds__(256)
void transpose_w(const float* __restrict__ W, unsigned short* __restrict__ Wt)
{
    int idx = blockIdx.x * 256 + threadIdx.x;   // 65536 total
    int n = idx >> 7, k = idx & 127;
    Wt[idx] = f2bf(W[k * 512 + n]);
}

// ---------------- K1: MFMA feat GEMM ----------------------------------------
__device__ __forceinline__ short8 pack_bf8(float4 a, float4 b){
    short8 r;
    r[0] = (short)f2bf(a.x); r[1] = (short)f2bf(a.y);
    r[2] = (short)f2bf(a.z); r[3] = (short)f2bf(a.w);
    r[4] = (short)f2bf(b.x); r[5] = (short)f2bf(b.y);
    r[6] = (short)f2bf(b.z); r[7] = (short)f2bf(b.w);
    return r;
}

__global__ __launch_bounds__(256)
void feat_gemm_mfma(const float* __restrict__ node_emb,
                    const int* __restrict__ ids,
                    const unsigned short* __restrict__ Wt,   // [512][128] bf16
                    const float* __restrict__ bias,
                    unsigned short* __restrict__ out,        // [M][512] bf16
                    int M)
{
    const int t    = threadIdx.x;
    const int lane = t & 63;
    const int w    = t >> 6;
    const int quad = lane >> 4;
    const int l15  = lane & 15;
    const int m0   = blockIdx.x * 64;

    int arowi = m0 + w * 16 + l15;
    if (arowi > M - 1) arowi = M - 1;
    const float* arow = node_emb + (size_t)ids[arowi] * 128;

    short8 afrag[4];
    #pragma unroll
    for (int s = 0; s < 4; s++){
        float4 v0 = *(const float4*)(arow + s * 32 + quad * 8);
        float4 v1 = *(const float4*)(arow + s * 32 + quad * 8 + 4);
        afrag[s] = pack_bf8(v0, v1);
    }

    for (int sl = 0; sl < 8; sl++){
        const int n0 = sl * 64;
        short8 bfrag[4][4];
        #pragma unroll
        for (int s = 0; s < 4; s++)
            #pragma unroll
            for (int c = 0; c < 4; c++)
                bfrag[s][c] = *(const short8*)(Wt + (size_t)(n0 + c * 16 + l15) * 128
                                               + s * 32 + quad * 8);
        f32x4 acc[4];
        #pragma unroll
        for (int c = 0; c < 4; c++) acc[c] = (f32x4){0.f, 0.f, 0.f, 0.f};
        #pragma unroll
        for (int s = 0; s < 4; s++)
            #pragma unroll
            for (int c = 0; c < 4; c++)
                acc[c] = __builtin_amdgcn_mfma_f32_16x16x32_bf16(
                             afrag[s], bfrag[s][c], acc[c], 0, 0, 0);
        #pragma unroll
        for (int c = 0; c < 4; c++){
            int colg = n0 + c * 16 + l15;
            float bv = bias[colg];
            #pragma unroll
            for (int r = 0; r < 4; r++){
                int rowg = m0 + w * 16 + quad * 4 + r;
                if (rowg < M)
                    out[(size_t)rowg * 512 + colg] = f2bf(acc[c][r] + bv);
            }
        }
    }
}

// ---------------- K2/K3/K4: counting sort by dst ----------------------------
__global__ __launch_bounds__(256)
void hist_kernel(const int* __restrict__ edst, int* __restrict__ cnt, int E)
{
    int idx = blockIdx.x * 256 + threadIdx.x;
    if (idx < E) atomicAdd(&cnt[edst[idx]], 1);
}

__global__ __launch_bounds__(1024)
void scan_kernel(const int* __restrict__ cnt,
                 int* __restrict__ start,
                 int* __restrict__ cursor)
{
    __shared__ int sums[1024];
    const int t = threadIdx.x;
    const int CHUNK = (NBINS + 1023) / 1024;
    int lo = t * CHUNK;
    int hi = lo + CHUNK; if (hi > NBINS) hi = NBINS;
    int s = 0;
    for (int i = lo; i < hi; i++) s += cnt[i];
    sums[t] = s;
    __syncthreads();
    for (int off = 1; off < 1024; off <<= 1){
        int v = sums[t];
        int add = (t >= off) ? sums[t - off] : 0;
        __syncthreads();
        sums[t] = v + add;
        __syncthreads();
    }
    int run = (t == 0) ? 0 : sums[t - 1];
    for (int i = lo; i < hi; i++){
        start[i] = run;
        cursor[i] = run;
        run += cnt[i];
    }
    if (t == 1023) start[NBINS] = sums[1023];
}

// s64[pos] = (src << 27) | (edge_id << 5) | rtype   (17 + 22 + 5 = 44 bits)
__global__ __launch_bounds__(256)
void scatter_kernel(const int* __restrict__ edst,
                    const int* __restrict__ ert,
                    const int* __restrict__ esrc,
                    int* __restrict__ cursor,
                    unsigned long long* __restrict__ s64,
                    int E)
{
    int idx = blockIdx.x * 256 + threadIdx.x;
    if (idx < E){
        int pos = atomicAdd(&cursor[edst[idx]], 1);
        s64[pos] = ((unsigned long long)esrc[idx] << 27)
                 | (unsigned)((idx << 5) | ert[idx]);
    }
}

// ---------------- K5: fused per-dst edge stage ------------------------------
__device__ __forceinline__ float logit_part(uint4 u, const float* fdv, const float* ar){
    unsigned uu[4] = {u.x, u.y, u.z, u.w};
    float p = 0.f;
    #pragma unroll
    for (int q = 0; q < 4; q++){
        float e0 = bflo(uu[q]) + fdv[2*q];
        float e1 = bfhi(uu[q]) + fdv[2*q+1];
        e0 = fmaxf(e0, 0.2f * e0);
        e1 = fmaxf(e1, 0.2f * e1);
        p = fmaf(e0, ar[2*q],   p);
        p = fmaf(e1, ar[2*q+1], p);
    }
    return p;
}

__device__ __forceinline__ float msg_ev(uint4 u, const float* rr, float a, float* ev){
    unsigned uu[4] = {u.x, u.y, u.z, u.w};
    float ss = 0.f;
    #pragma unroll
    for (int q = 0; q < 4; q++){
        float v0 = bflo(uu[q]) * rr[2*q]   * a;
        float v1 = bfhi(uu[q]) * rr[2*q+1] * a;
        ev[2*q]   = __expf(v0);
        ev[2*q+1] = __expf(v1);
        ss += ev[2*q] + ev[2*q+1];
    }
    return ss;
}

__global__ __launch_bounds__(256)
void fused_edge(const unsigned short* __restrict__ fs,
                const unsigned short* __restrict__ fd,
                const float* __restrict__ rel,
                const unsigned long long* __restrict__ s64,
                const int* __restrict__ start,
                const float* __restrict__ attn,
                float* __restrict__ att_out,
                float* __restrict__ gout)
{
    const int lane = threadIdx.x & 63;
    const int h    = lane >> 4;
    const int g16  = lane & 15;
    const int d0   = g16 * 8;
    const int dt   = blockIdx.x * 4 + (threadIdx.x >> 6);
    if (dt >= NN_DST) return;

    float ar[8];
    #pragma unroll
    for (int j = 0; j < 8; j++) ar[j] = attn[h * 128 + d0 + j];

    const uint4 du = *(const uint4*)(fd + (size_t)dt * 512 + h * 128 + d0);
    const unsigned udv[4] = {du.x, du.y, du.z, du.w};
    float fdv[8];
    #pragma unroll
    for (int q = 0; q < 4; q++){ fdv[2*q] = bflo(udv[q]); fdv[2*q+1] = bfhi(udv[q]); }

    const int beg = start[dt];
    const int end = start[dt + 1];

    // ---- pass 1: denominator only — no stores, 4 fs rows in flight ---------
    float den = 0.f;
    int i = beg;
    for (; i + 4 <= end; i += 4){
        unsigned long long p0 = s64[i],     p1 = s64[i + 1];
        unsigned long long p2 = s64[i + 2], p3 = s64[i + 3];
        uint4 u0 = *(const uint4*)(fs + (size_t)(p0 >> 27) * 512 + h * 128 + d0);
        uint4 u1 = *(const uint4*)(fs + (size_t)(p1 >> 27) * 512 + h * 128 + d0);
        uint4 u2 = *(const uint4*)(fs + (size_t)(p2 >> 27) * 512 + h * 128 + d0);
        uint4 u3 = *(const uint4*)(fs + (size_t)(p3 >> 27) * 512 + h * 128 + d0);
        float pa = logit_part(u0, fdv, ar);
        float pb = logit_part(u1, fdv, ar);
        float pc = logit_part(u2, fdv, ar);
        float pd = logit_part(u3, fdv, ar);
        pa += __shfl_xor(pa, 1); pb += __shfl_xor(pb, 1);
        pc += __shfl_xor(pc, 1); pd += __shfl_xor(pd, 1);
        pa += __shfl_xor(pa, 2); pb += __shfl_xor(pb, 2);
        pc += __shfl_xor(pc, 2); pd += __shfl_xor(pd, 2);
        pa += __shfl_xor(pa, 4); pb += __shfl_xor(pb, 4);
        pc += __shfl_xor(pc, 4); pd += __shfl_xor(pd, 4);
        pa += __shfl_xor(pa, 8); pb += __shfl_xor(pb, 8);
        pc += __shfl_xor(pc, 8); pd += __shfl_xor(pd, 8);
        den += __expf(pa) + __expf(pb) + __expf(pc) + __expf(pd);
    }
    for (; i < end; i++){
        unsigned long long p0 = s64[i];
        uint4 u0 = *(const uint4*)(fs + (size_t)(p0 >> 27) * 512 + h * 128 + d0);
        float pa = logit_part(u0, fdv, ar);
        pa += __shfl_xor(pa, 1);
        pa += __shfl_xor(pa, 2);
        pa += __shfl_xor(pa, 4);
        pa += __shfl_xor(pa, 8);
        den += __expf(pa);
    }
    const float invden = 1.0f / (den + 1e-16f);

    // ---- pass 2: recompute logit from in-register row, message, g ----------
    float acc[8];
    #pragma unroll
    for (int j = 0; j < 8; j++) acc[j] = 0.f;

    i = beg;
    for (; i + 2 <= end; i += 2){
        unsigned long long p0 = s64[i], p1 = s64[i + 1];
        int e0  = (int)((p0 >> 5) & 0x3FFFFF);
        int e1  = (int)((p1 >> 5) & 0x3FFFFF);
        int rt0 = (int)(p0 & 31), rt1 = (int)(p1 & 31);
        uint4 ua = *(const uint4*)(fs + (size_t)(p0 >> 27) * 512 + h * 128 + d0);
        uint4 ub = *(const uint4*)(fs + (size_t)(p1 >> 27) * 512 + h * 128 + d0);
        float4 ra0 = *(const float4*)(rel + rt0 * 128 + d0);
        float4 ra1 = *(const float4*)(rel + rt0 * 128 + d0 + 4);
        float4 rb0 = *(const float4*)(rel + rt1 * 128 + d0);
        float4 rb1 = *(const float4*)(rel + rt1 * 128 + d0 + 4);
        float pa = logit_part(ua, fdv, ar);
        float pb = logit_part(ub, fdv, ar);
        pa += __shfl_xor(pa, 1);  pb += __shfl_xor(pb, 1);
        pa += __shfl_xor(pa, 2);  pb += __shfl_xor(pb, 2);
        pa += __shfl_xor(pa, 4);  pb += __shfl_xor(pb, 4);
        pa += __shfl_xor(pa, 8);  pb += __shfl_xor(pb, 8);
        float aa = __expf(pa) * invden;
        float ab = __expf(pb) * invden;
        if (g16 == 0){
            att_out[(size_t)e0 * 4 + h] = aa;
            att_out[(size_t)e1 * 4 + h] = ab;
        }
        float rra[8] = {ra0.x, ra0.y, ra0.z, ra0.w, ra1.x, ra1.y, ra1.z, ra1.w};
        float rrb[8] = {rb0.x, rb0.y, rb0.z, rb0.w, rb1.x, rb1.y, rb1.z, rb1.w};
        float eva[8], evb[8];
        float sa = msg_ev(ua, rra, aa, eva);
        float sb = msg_ev(ub, rrb, ab, evb);
        sa += __shfl_xor(sa, 1);  sb += __shfl_xor(sb, 1);
        sa += __shfl_xor(sa, 2);  sb += __shfl_xor(sb, 2);
        sa += __shfl_xor(sa, 4);  sb += __shfl_xor(sb, 4);
        sa += __shfl_xor(sa, 8);  sb += __shfl_xor(sb, 8);
        float ia = 1.0f / sa, ib = 1.0f / sb;
        #pragma unroll
        for (int j = 0; j < 8; j++){
            acc[j] = fmaf(eva[j], ia, acc[j]);
            acc[j] = fmaf(evb[j], ib, acc[j]);
        }
    }
    if (i < end){
        unsigned long long p0 = s64[i];
        int e0  = (int)((p0 >> 5) & 0x3FFFFF);
        int rt0 = (int)(p0 & 31);
        uint4 ua = *(const uint4*)(fs + (size_t)(p0 >> 27) * 512 + h * 128 + d0);
        float4 ra0 = *(const float4*)(rel + rt0 * 128 + d0);
        float4 ra1 = *(const float4*)(rel + rt0 * 128 + d0 + 4);
        float pa = logit_part(ua, fdv, ar);
        pa += __shfl_xor(pa, 1);
        pa += __shfl_xor(pa, 2);
        pa += __shfl_xor(pa, 4);
        pa += __shfl_xor(pa, 8);
        float aa = __expf(pa) * invden;
        if (g16 == 0) att_out[(size_t)e0 * 4 + h] = aa;
        float rra[8] = {ra0.x, ra0.y, ra0.z, ra0.w, ra1.x, ra1.y, ra1.z, ra1.w};
        float eva[8];
        float sa = msg_ev(ua, rra, aa, eva);
        sa += __shfl_xor(sa, 1);
        sa += __shfl_xor(sa, 2);
        sa += __shfl_xor(sa, 4);
        sa += __shfl_xor(sa, 8);
        float ia = 1.0f / sa;
        #pragma unroll
        for (int j = 0; j < 8; j++) acc[j] = fmaf(eva[j], ia, acc[j]);
    }

    #pragma unroll
    for (int j = 0; j < 8; j++){
        acc[j] += __shfl_xor(acc[j], 16);
        acc[j] += __shfl_xor(acc[j], 32);
    }
    if (lane < 16){
        float4 o0 = make_float4(acc[0], acc[1], acc[2], acc[3]);
        float4 o1 = make_float4(acc[4], acc[5], acc[6], acc[7]);
        *(float4*)(gout + (size_t)dt * 128 + d0)     = o0;
        *(float4*)(gout + (size_t)dt * 128 + d0 + 4) = o1;
    }
}

// ---------------- K6: final SIMT GEMM ---------------------------------------
__global__ __launch_bounds__(256)
void final_gemm(const float* __restrict__ node_emb,
                const int* __restrict__ ids,
                const float* __restrict__ gbuf,
                const float* __restrict__ W1,
                const float* __restrict__ b1,
                float* __restrict__ xout,
                float* __restrict__ embcat,
                int M)
{
    __shared__ float Alds[64][132];
    const int t = threadIdx.x;
    const int row0 = blockIdx.x * 64;

    #pragma unroll
    for (int i = 0; i < 8; i++){
        int j = t + i * 256;
        int r = j >> 5;
        int c4 = j & 31;
        int row = row0 + r;
        if (row > M - 1) row = M - 1;
        int nid = ids[row];
        float4 v  = ((const float4*)(node_emb + (size_t)nid * 128))[c4];
        float4 gv = ((const float4*)(gbuf + (size_t)row * 128))[c4];
        v.x += gv.x; v.y += gv.y; v.z += gv.z; v.w += gv.w;
        *(float4*)&Alds[r][c4 * 4] = v;
    }
    __syncthreads();

    const int tr = t >> 4;
    const int tc = t & 15;
    const int colbase = tc * 8;
    float acc[4][8];
    #pragma unroll
    for (int i = 0; i < 4; i++)
        #pragma unroll
        for (int j = 0; j < 8; j++) acc[i][j] = 0.f;

    const float* Wp = W1 + colbase;
    #pragma unroll 4
    for (int k = 0; k < 128; k += 4){
        float4 a0 = *(const float4*)&Alds[tr*4+0][k];
        float4 a1 = *(const float4*)&Alds[tr*4+1][k];
        float4 a2 = *(const float4*)&Alds[tr*4+2][k];
        float4 a3 = *(const float4*)&Alds[tr*4+3][k];
        #pragma unroll
        for (int kk = 0; kk < 4; kk++){
            float4 b0  = *(const float4*)(Wp + (k + kk) * 128);
            float4 b1v = *(const float4*)(Wp + (k + kk) * 128 + 4);
            float bb[8] = {b0.x,b0.y,b0.z,b0.w,b1v.x,b1v.y,b1v.z,b1v.w};
            float av[4] = { ((const float*)&a0)[kk], ((const float*)&a1)[kk],
                            ((const float*)&a2)[kk], ((const float*)&a3)[kk] };
            #pragma unroll
            for (int i = 0; i < 4; i++)
                #pragma unroll
                for (int j = 0; j < 8; j++)
                    acc[i][j] = fmaf(av[i], bb[j], acc[i][j]);
        }
    }

    float bs[8];
    #pragma unroll
    for (int j = 0; j < 8; j++) bs[j] = b1[colbase + j];
    #pragma unroll
    for (int i = 0; i < 4; i++){
        int row = row0 + tr * 4 + i;
        if (row < M){
            float o[8];
            #pragma unroll
            for (int j = 0; j < 8; j++){
                float y = acc[i][j] + bs[j];
                o[j] = fmaxf(y, 0.01f * y);
            }
            float4 o0 = make_float4(o[0], o[1], o[2], o[3]);
            float4 o1 = make_float4(o[4], o[5], o[6], o[7]);
            *(float4*)(xout   + (size_t)row * 128 + colbase)     = o0;
            *(float4*)(xout   + (size_t)row * 128 + colbase + 4) = o1;
            *(float4*)(embcat + (size_t)row * 128 + colbase)     = o0;
            *(float4*)(embcat + (size_t)row * 128 + colbase + 4) = o1;
        }
    }
}

extern "C" void kernel_launch(void* const* d_in, const int* in_sizes, int n_in,
                              void* d_out, int out_size, void* d_ws, size_t ws_size,
                              hipStream_t stream)
{
    const int*   src_ids    = (const int*)d_in[0];
    const int*   edge_src   = (const int*)d_in[1];
    const int*   edge_dst   = (const int*)d_in[2];
    const int*   edge_rtype = (const int*)d_in[3];
    const float* node_emb   = (const float*)d_in[4];
    const float* rel_emb    = (const float*)d_in[5];
    const float* w1_w       = (const float*)d_in[6];
    const float* w1_b       = (const float*)d_in[7];
    const float* w2s_w      = (const float*)d_in[8];
    const float* w2s_b      = (const float*)d_in[9];
    const float* w2d_w      = (const float*)d_in[10];
    const float* w2d_b      = (const float*)d_in[11];
    const float* attn       = (const float*)d_in[12];
    const int E = in_sizes[1];             // 3,200,000

    float* out      = (float*)d_out;
    float* x_out    = out;                          // 50000*128
    float* emb_cat  = out + (size_t)6400000;        // 50000*128
    float* g_out    = out + (size_t)12800000;       // 50000*128
    float* att_out  = out + (size_t)19200000;       // E*4

    char* ws = (char*)d_ws;
    unsigned short* feat_src = (unsigned short*)ws;                       // 102,400,000 B
    unsigned short* feat_dst = (unsigned short*)(ws + 102400000);         //  51,200,000 B
    int*  cnt    = (int*)(ws + 153600000);                                //     200,000 B
    int*  start  = (int*)(ws + 153800000);                                //     200,004 B
    int*  cursor = (int*)(ws + 154000008);                                //     200,000 B
    unsigned short* w2s_t = (unsigned short*)(ws + 154200008);            //     131,072 B
    unsigned short* w2d_t = (unsigned short*)(ws + 154331080);            //     131,072 B

    // sorted-edge uint64 array aliases the x_out output region:
    // E*8 = 25,600,000 B == 50000*128*4 B exactly. Written by K4, read by K5,
    // then x_out fully overwritten by K6 (same stream ordering).
    unsigned long long* s64 = (unsigned long long*)out;

    hipMemsetAsync(cnt, 0, NBINS * sizeof(int), stream);

    dim3 b256(256);
    transpose_w<<<256, b256, 0, stream>>>(w2s_w, w2s_t);
    transpose_w<<<256, b256, 0, stream>>>(w2d_w, w2d_t);
    feat_gemm_mfma<<<(NN_NODES + 63) / 64, b256, 0, stream>>>(
        node_emb, src_ids, w2s_t, w2s_b, feat_src, NN_NODES);
    feat_gemm_mfma<<<(NN_DST + 63) / 64, b256, 0, stream>>>(
        node_emb, src_ids, w2d_t, w2d_b, feat_dst, NN_DST);
    hist_kernel<<<(E + 255) / 256, b256, 0, stream>>>(edge_dst, cnt, E);
    scan_kernel<<<1, 1024, 0, stream>>>(cnt, start, cursor);
    scatter_kernel<<<(E + 255) / 256, b256, 0, stream>>>(
        edge_dst, edge_rtype, edge_src, cursor, s64, E);
    fused_edge<<<(NN_DST + 3) / 4, b256, 0, stream>>>(
        feat_src, feat_dst, rel_emb, s64, start, attn, att_out, g_out);
    final_gemm<<<(NN_DST + 63) / 64, b256, 0, stream>>>(
        node_emb, src_ids, g_out, w1_w, w1_b, x_out, emb_cat, NN_DST);
}

// Round 3
// 1817.686 us; speedup vs baseline: 1.1384x; 1.1384x over previous
//
#include <hip/hip_runtime.h>

// ---------------------------------------------------------------------------
// RGAT-like layer on MI355X — round 5.
// fused_edge was measured VALU-issue-bound (VALUBusy 88.8%, HBM 34%, MFMA 0).
// This round attacks VALU instruction count in K5:
//   - wave-uniform scalarization (readfirstlane dt; s_load for s64/start;
//     SALU field extraction; saddr-form gathers)
//   - packed f32 math (v_pk_add/mul/fma via float2 ext-vectors)
//   - v_rcp_f32 instead of precise division (2x per edge)
//   - DPP row_ror reduction (4 VALU adds) instead of ds_swizzle butterfly
// Scatter repacked: s64 = (src<<32) | (eid<<5) | rtype.
// ---------------------------------------------------------------------------

#define NN_NODES 100000
#define NN_DST   50000
#define NBINS    50000

typedef short short8 __attribute__((ext_vector_type(8)));
typedef float f32x4  __attribute__((ext_vector_type(4)));
typedef float f32x2  __attribute__((ext_vector_type(2)));

__device__ __forceinline__ unsigned short f2bf(float f){
    unsigned u = __float_as_uint(f);
    unsigned r = (u + 0x7FFFu + ((u >> 16) & 1u)) >> 16;
    return (unsigned short)r;
}
__device__ __forceinline__ f32x2 bf2(unsigned u){
    f32x2 r;
    r.x = __uint_as_float(u << 16);
    r.y = __uint_as_float(u & 0xFFFF0000u);
    return r;
}

// all-lanes sum within each 16-lane DPP row (groups match lane&15 layout)
__device__ __forceinline__ float rsum16(float x){
    int v;
    v = __builtin_amdgcn_update_dpp(0, __float_as_int(x), 0x121, 0xF, 0xF, false);
    x += __int_as_float(v);
    v = __builtin_amdgcn_update_dpp(0, __float_as_int(x), 0x122, 0xF, 0xF, false);
    x += __int_as_float(v);
    v = __builtin_amdgcn_update_dpp(0, __float_as_int(x), 0x124, 0xF, 0xF, false);
    x += __int_as_float(v);
    v = __builtin_amdgcn_update_dpp(0, __float_as_int(x), 0x128, 0xF, 0xF, false);
    x += __int_as_float(v);
    return x;
}

// ---------------- K0: W[128][512] fp32 -> Wt[512][128] bf16 -----------------
__global__ __launch_bounds__(256)
void transpose_w(const float* __restrict__ W, unsigned short* __restrict__ Wt)
{
    int idx = blockIdx.x * 256 + threadIdx.x;   // 65536 total
    int n = idx >> 7, k = idx & 127;
    Wt[idx] = f2bf(W[k * 512 + n]);
}

// ---------------- K1: MFMA feat GEMM ----------------------------------------
__device__ __forceinline__ short8 pack_bf8(float4 a, float4 b){
    short8 r;
    r[0] = (short)f2bf(a.x); r[1] = (short)f2bf(a.y);
    r[2] = (short)f2bf(a.z); r[3] = (short)f2bf(a.w);
    r[4] = (short)f2bf(b.x); r[5] = (short)f2bf(b.y);
    r[6] = (short)f2bf(b.z); r[7] = (short)f2bf(b.w);
    return r;
}

__global__ __launch_bounds__(256)
void feat_gemm_mfma(const float* __restrict__ node_emb,
                    const int* __restrict__ ids,
                    const unsigned short* __restrict__ Wt,   // [512][128] bf16
                    const float* __restrict__ bias,
                    unsigned short* __restrict__ out,        // [M][512] bf16
                    int M)
{
    const int t    = threadIdx.x;
    const int lane = t & 63;
    const int w    = t >> 6;
    const int quad = lane >> 4;
    const int l15  = lane & 15;
    const int m0   = blockIdx.x * 64;

    int arowi = m0 + w * 16 + l15;
    if (arowi > M - 1) arowi = M - 1;
    const float* arow = node_emb + (size_t)ids[arowi] * 128;

    short8 afrag[4];
    #pragma unroll
    for (int s = 0; s < 4; s++){
        float4 v0 = *(const float4*)(arow + s * 32 + quad * 8);
        float4 v1 = *(const float4*)(arow + s * 32 + quad * 8 + 4);
        afrag[s] = pack_bf8(v0, v1);
    }

    for (int sl = 0; sl < 8; sl++){
        const int n0 = sl * 64;
        short8 bfrag[4][4];
        #pragma unroll
        for (int s = 0; s < 4; s++)
            #pragma unroll
            for (int c = 0; c < 4; c++)
                bfrag[s][c] = *(const short8*)(Wt + (size_t)(n0 + c * 16 + l15) * 128
                                               + s * 32 + quad * 8);
        f32x4 acc[4];
        #pragma unroll
        for (int c = 0; c < 4; c++) acc[c] = (f32x4){0.f, 0.f, 0.f, 0.f};
        #pragma unroll
        for (int s = 0; s < 4; s++)
            #pragma unroll
            for (int c = 0; c < 4; c++)
                acc[c] = __builtin_amdgcn_mfma_f32_16x16x32_bf16(
                             afrag[s], bfrag[s][c], acc[c], 0, 0, 0);
        #pragma unroll
        for (int c = 0; c < 4; c++){
            int colg = n0 + c * 16 + l15;
            float bv = bias[colg];
            #pragma unroll
            for (int r = 0; r < 4; r++){
                int rowg = m0 + w * 16 + quad * 4 + r;
                if (rowg < M)
                    out[(size_t)rowg * 512 + colg] = f2bf(acc[c][r] + bv);
            }
        }
    }
}

// ---------------- K2/K3/K4: counting sort by dst ----------------------------
__global__ __launch_bounds__(256)
void hist_kernel(const int* __restrict__ edst, int* __restrict__ cnt, int E)
{
    int idx = blockIdx.x * 256 + threadIdx.x;
    if (idx < E) atomicAdd(&cnt[edst[idx]], 1);
}

__global__ __launch_bounds__(1024)
void scan_kernel(const int* __restrict__ cnt,
                 int* __restrict__ start,
                 int* __restrict__ cursor)
{
    __shared__ int sums[1024];
    const int t = threadIdx.x;
    const int CHUNK = (NBINS + 1023) / 1024;
    int lo = t * CHUNK;
    int hi = lo + CHUNK; if (hi > NBINS) hi = NBINS;
    int s = 0;
    for (int i = lo; i < hi; i++) s += cnt[i];
    sums[t] = s;
    __syncthreads();
    for (int off = 1; off < 1024; off <<= 1){
        int v = sums[t];
        int add = (t >= off) ? sums[t - off] : 0;
        __syncthreads();
        sums[t] = v + add;
        __syncthreads();
    }
    int run = (t == 0) ? 0 : sums[t - 1];
    for (int i = lo; i < hi; i++){
        start[i] = run;
        cursor[i] = run;
        run += cnt[i];
    }
    if (t == 1023) start[NBINS] = sums[1023];
}

// s64[pos] = (src << 32) | (edge_id << 5) | rtype
__global__ __launch_bounds__(256)
void scatter_kernel(const int* __restrict__ edst,
                    const int* __restrict__ ert,
                    const int* __restrict__ esrc,
                    int* __restrict__ cursor,
                    unsigned long long* __restrict__ s64,
                    int E)
{
    int idx = blockIdx.x * 256 + threadIdx.x;
    if (idx < E){
        int pos = atomicAdd(&cursor[edst[idx]], 1);
        s64[pos] = ((unsigned long long)esrc[idx] << 32)
                 | (unsigned)((idx << 5) | ert[idx]);
    }
}

// ---------------- K5: fused per-dst edge stage ------------------------------
__device__ __forceinline__ float logit_p(uint4 u, const f32x2* fd2, const f32x2* ar2){
    unsigned uu[4] = {u.x, u.y, u.z, u.w};
    f32x2 p = {0.f, 0.f};
    #pragma unroll
    for (int q = 0; q < 4; q++){
        f32x2 e  = bf2(uu[q]) + fd2[q];
        f32x2 e2 = __builtin_elementwise_max(e, e * 0.2f);
        p = __builtin_elementwise_fma(e2, ar2[q], p);
    }
    return p.x + p.y;
}

__device__ __forceinline__ f32x2 msg8(uint4 u, const f32x2* rr2, f32x2* ev){
    unsigned uu[4] = {u.x, u.y, u.z, u.w};
    f32x2 ss = {0.f, 0.f};
    #pragma unroll
    for (int q = 0; q < 4; q++){
        f32x2 v = bf2(uu[q]) * rr2[q];
        f32x2 e;
        e.x = __expf(v.x);
        e.y = __expf(v.y);
        ev[q] = e;
        ss += e;
    }
    return ss;
}

__global__ __launch_bounds__(256)
void fused_edge(const unsigned short* __restrict__ fs,
                const unsigned short* __restrict__ fd,
                const float* __restrict__ rel,
                const unsigned long long* __restrict__ s64,
                const int* __restrict__ start,
                const float* __restrict__ attn,
                float* __restrict__ att_out,
                float* __restrict__ gout)
{
    const int lane = threadIdx.x & 63;
    const int h    = lane >> 4;
    const int g16  = lane & 15;
    const int d0   = g16 * 8;
    const int loff = h * 128 + d0;               // element offset in 512-row

    // wave-uniform dst index -> SGPR; everything derived from it scalarizes
    const int dt = __builtin_amdgcn_readfirstlane(blockIdx.x * 4 + (threadIdx.x >> 6));
    if (dt >= NN_DST) return;

    f32x2 ar2[4], fd2[4];
    {
        float4 a0 = *(const float4*)(attn + loff);
        float4 a1 = *(const float4*)(attn + loff + 4);
        ar2[0] = (f32x2){a0.x, a0.y}; ar2[1] = (f32x2){a0.z, a0.w};
        ar2[2] = (f32x2){a1.x, a1.y}; ar2[3] = (f32x2){a1.z, a1.w};
        uint4 du = *(const uint4*)(fd + (size_t)dt * 512 + loff);
        fd2[0] = bf2(du.x); fd2[1] = bf2(du.y);
        fd2[2] = bf2(du.z); fd2[3] = bf2(du.w);
    }

    const int beg = start[dt];
    const int end = start[dt + 1];

    // ---- pass 1: denominator only (no stores) ------------------------------
    float den = 0.f;
    int i = beg;
    for (; i + 4 <= end; i += 4){
        unsigned r0 = (unsigned)(s64[i]     >> 32);
        unsigned r1 = (unsigned)(s64[i + 1] >> 32);
        unsigned r2 = (unsigned)(s64[i + 2] >> 32);
        unsigned r3 = (unsigned)(s64[i + 3] >> 32);
        uint4 u0 = *(const uint4*)(fs + (size_t)r0 * 512 + loff);
        uint4 u1 = *(const uint4*)(fs + (size_t)r1 * 512 + loff);
        uint4 u2 = *(const uint4*)(fs + (size_t)r2 * 512 + loff);
        uint4 u3 = *(const uint4*)(fs + (size_t)r3 * 512 + loff);
        float pa = rsum16(logit_p(u0, fd2, ar2));
        float pb = rsum16(logit_p(u1, fd2, ar2));
        float pc = rsum16(logit_p(u2, fd2, ar2));
        float pd = rsum16(logit_p(u3, fd2, ar2));
        den += __expf(pa) + __expf(pb) + __expf(pc) + __expf(pd);
    }
    for (; i < end; i++){
        unsigned r0 = (unsigned)(s64[i] >> 32);
        uint4 u0 = *(const uint4*)(fs + (size_t)r0 * 512 + loff);
        den += __expf(rsum16(logit_p(u0, fd2, ar2)));
    }
    const float invden = __builtin_amdgcn_rcpf(den + 1e-16f);

    // ---- pass 2: recompute logit, write att once, msg softmax, g -----------
    f32x2 acc2[4];
    #pragma unroll
    for (int q = 0; q < 4; q++) acc2[q] = (f32x2){0.f, 0.f};

    i = beg;
    for (; i + 2 <= end; i += 2){
        unsigned long long p0 = s64[i], p1 = s64[i + 1];
        unsigned lo0 = (unsigned)p0, lo1 = (unsigned)p1;
        unsigned sa0 = (unsigned)(p0 >> 32), sa1 = (unsigned)(p1 >> 32);
        int e0 = (int)(lo0 >> 5), e1 = (int)(lo1 >> 5);
        int rt0 = (int)(lo0 & 31), rt1 = (int)(lo1 & 31);

        uint4 ua = *(const uint4*)(fs + (size_t)sa0 * 512 + loff);
        uint4 ub = *(const uint4*)(fs + (size_t)sa1 * 512 + loff);
        float4 ra0 = *(const float4*)(rel + rt0 * 128 + d0);
        float4 ra1 = *(const float4*)(rel + rt0 * 128 + d0 + 4);
        float4 rb0 = *(const float4*)(rel + rt1 * 128 + d0);
        float4 rb1 = *(const float4*)(rel + rt1 * 128 + d0 + 4);

        float pa = rsum16(logit_p(ua, fd2, ar2));
        float pb = rsum16(logit_p(ub, fd2, ar2));
        float aa = __expf(pa) * invden;
        float ab = __expf(pb) * invden;
        if (g16 == 0){
            att_out[(size_t)e0 * 4 + h] = aa;
            att_out[(size_t)e1 * 4 + h] = ab;
        }

        f32x2 rra[4] = {{ra0.x, ra0.y}, {ra0.z, ra0.w}, {ra1.x, ra1.y}, {ra1.z, ra1.w}};
        f32x2 rrb[4] = {{rb0.x, rb0.y}, {rb0.z, rb0.w}, {rb1.x, rb1.y}, {rb1.z, rb1.w}};
        #pragma unroll
        for (int q = 0; q < 4; q++){ rra[q] *= aa; rrb[q] *= ab; }

        f32x2 eva[4], evb[4];
        f32x2 ssa = msg8(ua, rra, eva);
        f32x2 ssb = msg8(ub, rrb, evb);
        float sA = rsum16(ssa.x + ssa.y);
        float sB = rsum16(ssb.x + ssb.y);
        float iA = __builtin_amdgcn_rcpf(sA);
        float iB = __builtin_amdgcn_rcpf(sB);
        f32x2 iA2 = (f32x2){iA, iA}, iB2 = (f32x2){iB, iB};
        #pragma unroll
        for (int q = 0; q < 4; q++){
            acc2[q] = __builtin_elementwise_fma(eva[q], iA2, acc2[q]);
            acc2[q] = __builtin_elementwise_fma(evb[q], iB2, acc2[q]);
        }
    }
    if (i < end){
        unsigned long long p0 = s64[i];
        unsigned lo0 = (unsigned)p0;
        unsigned sa0 = (unsigned)(p0 >> 32);
        int e0 = (int)(lo0 >> 5);
        int rt0 = (int)(lo0 & 31);
        uint4 ua = *(const uint4*)(fs + (size_t)sa0 * 512 + loff);
        float4 ra0 = *(const float4*)(rel + rt0 * 128 + d0);
        float4 ra1 = *(const float4*)(rel + rt0 * 128 + d0 + 4);
        float pa = rsum16(logit_p(ua, fd2, ar2));
        float aa = __expf(pa) * invden;
        if (g16 == 0) att_out[(size_t)e0 * 4 + h] = aa;
        f32x2 rra[4] = {{ra0.x, ra0.y}, {ra0.z, ra0.w}, {ra1.x, ra1.y}, {ra1.z, ra1.w}};
        #pragma unroll
        for (int q = 0; q < 4; q++) rra[q] *= aa;
        f32x2 eva[4];
        f32x2 ssa = msg8(ua, rra, eva);
        float sA = rsum16(ssa.x + ssa.y);
        float iA = __builtin_amdgcn_rcpf(sA);
        f32x2 iA2 = (f32x2){iA, iA};
        #pragma unroll
        for (int q = 0; q < 4; q++)
            acc2[q] = __builtin_elementwise_fma(eva[q], iA2, acc2[q]);
    }

    // sum the 4 head groups (cross-row: keep shfl, only 16 ops per dst)
    float accs[8];
    #pragma unroll
    for (int q = 0; q < 4; q++){ accs[2*q] = acc2[q].x; accs[2*q+1] = acc2[q].y; }
    #pragma unroll
    for (int j = 0; j < 8; j++){
        accs[j] += __shfl_xor(accs[j], 16);
        accs[j] += __shfl_xor(accs[j], 32);
    }
    if (lane < 16){
        float4 o0 = make_float4(accs[0], accs[1], accs[2], accs[3]);
        float4 o1 = make_float4(accs[4], accs[5], accs[6], accs[7]);
        *(float4*)(gout + (size_t)dt * 128 + d0)     = o0;
        *(float4*)(gout + (size_t)dt * 128 + d0 + 4) = o1;
    }
}

// ---------------- K6: final SIMT GEMM ---------------------------------------
__global__ __launch_bounds__(256)
void final_gemm(const float* __restrict__ node_emb,
                const int* __restrict__ ids,
                const float* __restrict__ gbuf,
                const float* __restrict__ W1,
                const float* __restrict__ b1,
                float* __restrict__ xout,
                float* __restrict__ embcat,
                int M)
{
    __shared__ float Alds[64][132];
    const int t = threadIdx.x;
    const int row0 = blockIdx.x * 64;

    #pragma unroll
    for (int i = 0; i < 8; i++){
        int j = t + i * 256;
        int r = j >> 5;
        int c4 = j & 31;
        int row = row0 + r;
        if (row > M - 1) row = M - 1;
        int nid = ids[row];
        float4 v  = ((const float4*)(node_emb + (size_t)nid * 128))[c4];
        float4 gv = ((const float4*)(gbuf + (size_t)row * 128))[c4];
        v.x += gv.x; v.y += gv.y; v.z += gv.z; v.w += gv.w;
        *(float4*)&Alds[r][c4 * 4] = v;
    }
    __syncthreads();

    const int tr = t >> 4;
    const int tc = t & 15;
    const int colbase = tc * 8;
    float acc[4][8];
    #pragma unroll
    for (int i = 0; i < 4; i++)
        #pragma unroll
        for (int j = 0; j < 8; j++) acc[i][j] = 0.f;

    const float* Wp = W1 + colbase;
    #pragma unroll 4
    for (int k = 0; k < 128; k += 4){
        float4 a0 = *(const float4*)&Alds[tr*4+0][k];
        float4 a1 = *(const float4*)&Alds[tr*4+1][k];
        float4 a2 = *(const float4*)&Alds[tr*4+2][k];
        float4 a3 = *(const float4*)&Alds[tr*4+3][k];
        #pragma unroll
        for (int kk = 0; kk < 4; kk++){
            float4 b0  = *(const float4*)(Wp + (k + kk) * 128);
            float4 b1v = *(const float4*)(Wp + (k + kk) * 128 + 4);
            float bb[8] = {b0.x,b0.y,b0.z,b0.w,b1v.x,b1v.y,b1v.z,b1v.w};
            float av[4] = { ((const float*)&a0)[kk], ((const float*)&a1)[kk],
                            ((const float*)&a2)[kk], ((const float*)&a3)[kk] };
            #pragma unroll
            for (int i = 0; i < 4; i++)
                #pragma unroll
                for (int j = 0; j < 8; j++)
                    acc[i][j] = fmaf(av[i], bb[j], acc[i][j]);
        }
    }

    float bs[8];
    #pragma unroll
    for (int j = 0; j < 8; j++) bs[j] = b1[colbase + j];
    #pragma unroll
    for (int i = 0; i < 4; i++){
        int row = row0 + tr * 4 + i;
        if (row < M){
            float o[8];
            #pragma unroll
            for (int j = 0; j < 8; j++){
                float y = acc[i][j] + bs[j];
                o[j] = fmaxf(y, 0.01f * y);
            }
            float4 o0 = make_float4(o[0], o[1], o[2], o[3]);
            float4 o1 = make_float4(o[4], o[5], o[6], o[7]);
            *(float4*)(xout   + (size_t)row * 128 + colbase)     = o0;
            *(float4*)(xout   + (size_t)row * 128 + colbase + 4) = o1;
            *(float4*)(embcat + (size_t)row * 128 + colbase)     = o0;
            *(float4*)(embcat + (size_t)row * 128 + colbase + 4) = o1;
        }
    }
}

extern "C" void kernel_launch(void* const* d_in, const int* in_sizes, int n_in,
                              void* d_out, int out_size, void* d_ws, size_t ws_size,
                              hipStream_t stream)
{
    const int*   src_ids    = (const int*)d_in[0];
    const int*   edge_src   = (const int*)d_in[1];
    const int*   edge_dst   = (const int*)d_in[2];
    const int*   edge_rtype = (const int*)d_in[3];
    const float* node_emb   = (const float*)d_in[4];
    const float* rel_emb    = (const float*)d_in[5];
    const float* w1_w       = (const float*)d_in[6];
    const float* w1_b       = (const float*)d_in[7];
    const float* w2s_w      = (const float*)d_in[8];
    const float* w2s_b      = (const float*)d_in[9];
    const float* w2d_w      = (const float*)d_in[10];
    const float* w2d_b      = (const float*)d_in[11];
    const float* attn       = (const float*)d_in[12];
    const int E = in_sizes[1];             // 3,200,000

    float* out      = (float*)d_out;
    float* x_out    = out;                          // 50000*128
    float* emb_cat  = out + (size_t)6400000;        // 50000*128
    float* g_out    = out + (size_t)12800000;       // 50000*128
    float* att_out  = out + (size_t)19200000;       // E*4

    char* ws = (char*)d_ws;
    unsigned short* feat_src = (unsigned short*)ws;                       // 102,400,000 B
    unsigned short* feat_dst = (unsigned short*)(ws + 102400000);         //  51,200,000 B
    int*  cnt    = (int*)(ws + 153600000);                                //     200,000 B
    int*  start  = (int*)(ws + 153800000);                                //     200,004 B
    int*  cursor = (int*)(ws + 154000008);                                //     200,000 B
    unsigned short* w2s_t = (unsigned short*)(ws + 154200008);            //     131,072 B
    unsigned short* w2d_t = (unsigned short*)(ws + 154331080);            //     131,072 B

    // sorted-edge uint64 array aliases the x_out output region:
    // E*8 = 25,600,000 B == 50000*128*4 B exactly. Written by K4, read by K5,
    // then x_out fully overwritten by K6 (same stream ordering).
    unsigned long long* s64 = (unsigned long long*)out;

    hipMemsetAsync(cnt, 0, NBINS * sizeof(int), stream);

    dim3 b256(256);
    transpose_w<<<256, b256, 0, stream>>>(w2s_w, w2s_t);
    transpose_w<<<256, b256, 0, stream>>>(w2d_w, w2d_t);
    feat_gemm_mfma<<<(NN_NODES + 63) / 64, b256, 0, stream>>>(
        node_emb, src_ids, w2s_t, w2s_b, feat_src, NN_NODES);
    feat_gemm_mfma<<<(NN_DST + 63) / 64, b256, 0, stream>>>(
        node_emb, src_ids, w2d_t, w2d_b, feat_dst, NN_DST);
    hist_kernel<<<(E + 255) / 256, b256, 0, stream>>>(edge_dst, cnt, E);
    scan_kernel<<<1, 1024, 0, stream>>>(cnt, start, cursor);
    scatter_kernel<<<(E + 255) / 256, b256, 0, stream>>>(
        edge_dst, edge_rtype, edge_src, cursor, s64, E);
    fused_edge<<<(NN_DST + 3) / 4, b256, 0, stream>>>(
        feat_src, feat_dst, rel_emb, s64, start, attn, att_out, g_out);
    final_gemm<<<(NN_DST + 63) / 64, b256, 0, stream>>>(
        node_emb, src_ids, g_out, w1_w, w1_b, x_out, emb_cat, NN_DST);
}

// Round 4
// 1809.264 us; speedup vs baseline: 1.1437x; 1.0047x over previous
//
#include <hip/hip_runtime.h>

// ---------------------------------------------------------------------------
// RGAT-like layer on MI355X — round 6.
// fused_edge still VALU-bound (VALUBusy 80%, HBM 45%, MFMA 0, LDS 0).
// This round: (1) pass-1 ex values cached in LDS (per-dst degree ~64), so
// pass 2 reads ex via broadcast ds_read instead of recomputing the full
// logit (bf2 unpack + pk_fma dot + DPP reduce + exp ~ 35-40 insts/edge);
// (2) exp2-folding: log2e folded into attn (per-dst) and into the a*rr
// scale (per-edge, mul already exists) -> all exps become bare v_exp_f32.
// Cold fallback recomputes logits for degree > 320 (never hit for random
// multinomial E=3.2M over 50k bins, max deg ~110).
// ---------------------------------------------------------------------------

#define NN_NODES 100000
#define NN_DST   50000
#define NBINS    50000
#define SLOTS    320
#define LOG2E    1.44269504088896f

typedef short short8 __attribute__((ext_vector_type(8)));
typedef float f32x4  __attribute__((ext_vector_type(4)));
typedef float f32x2  __attribute__((ext_vector_type(2)));

__device__ __forceinline__ unsigned short f2bf(float f){
    unsigned u = __float_as_uint(f);
    unsigned r = (u + 0x7FFFu + ((u >> 16) & 1u)) >> 16;
    return (unsigned short)r;
}
__device__ __forceinline__ f32x2 bf2(unsigned u){
    f32x2 r;
    r.x = __uint_as_float(u << 16);
    r.y = __uint_as_float(u & 0xFFFF0000u);
    return r;
}

// all-lanes sum within each 16-lane DPP row (groups match lane&15 layout)
__device__ __forceinline__ float rsum16(float x){
    int v;
    v = __builtin_amdgcn_update_dpp(0, __float_as_int(x), 0x121, 0xF, 0xF, false);
    x += __int_as_float(v);
    v = __builtin_amdgcn_update_dpp(0, __float_as_int(x), 0x122, 0xF, 0xF, false);
    x += __int_as_float(v);
    v = __builtin_amdgcn_update_dpp(0, __float_as_int(x), 0x124, 0xF, 0xF, false);
    x += __int_as_float(v);
    v = __builtin_amdgcn_update_dpp(0, __float_as_int(x), 0x128, 0xF, 0xF, false);
    x += __int_as_float(v);
    return x;
}

// ---------------- K0: W[128][512] fp32 -> Wt[512][128] bf16 -----------------
__global__ __launch_bounds__(256)
void transpose_w(const float* __restrict__ W, unsigned short* __restrict__ Wt)
{
    int idx = blockIdx.x * 256 + threadIdx.x;   // 65536 total
    int n = idx >> 7, k = idx & 127;
    Wt[idx] = f2bf(W[k * 512 + n]);
}

// ---------------- K1: MFMA feat GEMM ----------------------------------------
__device__ __forceinline__ short8 pack_bf8(float4 a, float4 b){
    short8 r;
    r[0] = (short)f2bf(a.x); r[1] = (short)f2bf(a.y);
    r[2] = (short)f2bf(a.z); r[3] = (short)f2bf(a.w);
    r[4] = (short)f2bf(b.x); r[5] = (short)f2bf(b.y);
    r[6] = (short)f2bf(b.z); r[7] = (short)f2bf(b.w);
    return r;
}

__global__ __launch_bounds__(256)
void feat_gemm_mfma(const float* __restrict__ node_emb,
                    const int* __restrict__ ids,
                    const unsigned short* __restrict__ Wt,   // [512][128] bf16
                    const float* __restrict__ bias,
                    unsigned short* __restrict__ out,        // [M][512] bf16
                    int M)
{
    const int t    = threadIdx.x;
    const int lane = t & 63;
    const int w    = t >> 6;
    const int quad = lane >> 4;
    const int l15  = lane & 15;
    const int m0   = blockIdx.x * 64;

    int arowi = m0 + w * 16 + l15;
    if (arowi > M - 1) arowi = M - 1;
    const float* arow = node_emb + (size_t)ids[arowi] * 128;

    short8 afrag[4];
    #pragma unroll
    for (int s = 0; s < 4; s++){
        float4 v0 = *(const float4*)(arow + s * 32 + quad * 8);
        float4 v1 = *(const float4*)(arow + s * 32 + quad * 8 + 4);
        afrag[s] = pack_bf8(v0, v1);
    }

    for (int sl = 0; sl < 8; sl++){
        const int n0 = sl * 64;
        short8 bfrag[4][4];
        #pragma unroll
        for (int s = 0; s < 4; s++)
            #pragma unroll
            for (int c = 0; c < 4; c++)
                bfrag[s][c] = *(const short8*)(Wt + (size_t)(n0 + c * 16 + l15) * 128
                                               + s * 32 + quad * 8);
        f32x4 acc[4];
        #pragma unroll
        for (int c = 0; c < 4; c++) acc[c] = (f32x4){0.f, 0.f, 0.f, 0.f};
        #pragma unroll
        for (int s = 0; s < 4; s++)
            #pragma unroll
            for (int c = 0; c < 4; c++)
                acc[c] = __builtin_amdgcn_mfma_f32_16x16x32_bf16(
                             afrag[s], bfrag[s][c], acc[c], 0, 0, 0);
        #pragma unroll
        for (int c = 0; c < 4; c++){
            int colg = n0 + c * 16 + l15;
            float bv = bias[colg];
            #pragma unroll
            for (int r = 0; r < 4; r++){
                int rowg = m0 + w * 16 + quad * 4 + r;
                if (rowg < M)
                    out[(size_t)rowg * 512 + colg] = f2bf(acc[c][r] + bv);
            }
        }
    }
}

// ---------------- K2/K3/K4: counting sort by dst ----------------------------
__global__ __launch_bounds__(256)
void hist_kernel(const int* __restrict__ edst, int* __restrict__ cnt, int E)
{
    int idx = blockIdx.x * 256 + threadIdx.x;
    if (idx < E) atomicAdd(&cnt[edst[idx]], 1);
}

__global__ __launch_bounds__(1024)
void scan_kernel(const int* __restrict__ cnt,
                 int* __restrict__ start,
                 int* __restrict__ cursor)
{
    __shared__ int sums[1024];
    const int t = threadIdx.x;
    const int CHUNK = (NBINS + 1023) / 1024;
    int lo = t * CHUNK;
    int hi = lo + CHUNK; if (hi > NBINS) hi = NBINS;
    int s = 0;
    for (int i = lo; i < hi; i++) s += cnt[i];
    sums[t] = s;
    __syncthreads();
    for (int off = 1; off < 1024; off <<= 1){
        int v = sums[t];
        int add = (t >= off) ? sums[t - off] : 0;
        __syncthreads();
        sums[t] = v + add;
        __syncthreads();
    }
    int run = (t == 0) ? 0 : sums[t - 1];
    for (int i = lo; i < hi; i++){
        start[i] = run;
        cursor[i] = run;
        run += cnt[i];
    }
    if (t == 1023) start[NBINS] = sums[1023];
}

// s64[pos] = (src << 32) | (edge_id << 5) | rtype
__global__ __launch_bounds__(256)
void scatter_kernel(const int* __restrict__ edst,
                    const int* __restrict__ ert,
                    const int* __restrict__ esrc,
                    int* __restrict__ cursor,
                    unsigned long long* __restrict__ s64,
                    int E)
{
    int idx = blockIdx.x * 256 + threadIdx.x;
    if (idx < E){
        int pos = atomicAdd(&cursor[edst[idx]], 1);
        s64[pos] = ((unsigned long long)esrc[idx] << 32)
                 | (unsigned)((idx << 5) | ert[idx]);
    }
}

// ---------------- K5: fused per-dst edge stage ------------------------------
// ar2 pre-scaled by LOG2E -> logit p is in log2 domain; ex = exp2(p).
__device__ __forceinline__ float logit_p(uint4 u, const f32x2* fd2, const f32x2* ar2){
    unsigned uu[4] = {u.x, u.y, u.z, u.w};
    f32x2 p = {0.f, 0.f};
    #pragma unroll
    for (int q = 0; q < 4; q++){
        f32x2 e  = bf2(uu[q]) + fd2[q];
        f32x2 e2 = __builtin_elementwise_max(e, e * 0.2f);
        p = __builtin_elementwise_fma(e2, ar2[q], p);
    }
    return p.x + p.y;
}

// rr2 pre-scaled by a*LOG2E -> message exps are bare exp2.
__device__ __forceinline__ f32x2 msg8(uint4 u, const f32x2* rr2, f32x2* ev){
    unsigned uu[4] = {u.x, u.y, u.z, u.w};
    f32x2 ss = {0.f, 0.f};
    #pragma unroll
    for (int q = 0; q < 4; q++){
        f32x2 v = bf2(uu[q]) * rr2[q];
        f32x2 e;
        e.x = __builtin_amdgcn_exp2f(v.x);
        e.y = __builtin_amdgcn_exp2f(v.y);
        ev[q] = e;
        ss += e;
    }
    return ss;
}

__global__ __launch_bounds__(256)
void fused_edge(const unsigned short* __restrict__ fs,
                const unsigned short* __restrict__ fd,
                const float* __restrict__ rel,
                const unsigned long long* __restrict__ s64,
                const int* __restrict__ start,
                const float* __restrict__ attn,
                float* __restrict__ att_out,
                float* __restrict__ gout)
{
    __shared__ float exls[4][SLOTS * 4];        // [wave][slot*4+h] = 20,480 B

    const int lane = threadIdx.x & 63;
    const int h    = lane >> 4;
    const int g16  = lane & 15;
    const int d0   = g16 * 8;
    const int loff = h * 128 + d0;               // element offset in 512-row
    const int wv   = threadIdx.x >> 6;
    float* exw = &exls[wv][0];

    // wave-uniform dst index -> SGPR; everything derived from it scalarizes
    const int dt = __builtin_amdgcn_readfirstlane(blockIdx.x * 4 + wv);
    if (dt >= NN_DST) return;

    f32x2 ar2[4], fd2[4];
    {
        float4 a0 = *(const float4*)(attn + loff);
        float4 a1 = *(const float4*)(attn + loff + 4);
        ar2[0] = (f32x2){a0.x, a0.y} * LOG2E; ar2[1] = (f32x2){a0.z, a0.w} * LOG2E;
        ar2[2] = (f32x2){a1.x, a1.y} * LOG2E; ar2[3] = (f32x2){a1.z, a1.w} * LOG2E;
        uint4 du = *(const uint4*)(fd + (size_t)dt * 512 + loff);
        fd2[0] = bf2(du.x); fd2[1] = bf2(du.y);
        fd2[2] = bf2(du.z); fd2[3] = bf2(du.w);
    }

    const int beg = start[dt];
    const int end = start[dt + 1];

    // ---- pass 1: denominator + LDS-cached ex -------------------------------
    float den = 0.f;
    int i = beg, k = 0;
    for (; i + 4 <= end; i += 4, k += 4){
        unsigned r0 = (unsigned)(s64[i]     >> 32);
        unsigned r1 = (unsigned)(s64[i + 1] >> 32);
        unsigned r2 = (unsigned)(s64[i + 2] >> 32);
        unsigned r3 = (unsigned)(s64[i + 3] >> 32);
        uint4 u0 = *(const uint4*)(fs + (size_t)r0 * 512 + loff);
        uint4 u1 = *(const uint4*)(fs + (size_t)r1 * 512 + loff);
        uint4 u2 = *(const uint4*)(fs + (size_t)r2 * 512 + loff);
        uint4 u3 = *(const uint4*)(fs + (size_t)r3 * 512 + loff);
        float xa = __builtin_amdgcn_exp2f(rsum16(logit_p(u0, fd2, ar2)));
        float xb = __builtin_amdgcn_exp2f(rsum16(logit_p(u1, fd2, ar2)));
        float xc = __builtin_amdgcn_exp2f(rsum16(logit_p(u2, fd2, ar2)));
        float xd = __builtin_amdgcn_exp2f(rsum16(logit_p(u3, fd2, ar2)));
        den += xa + xb + xc + xd;
        if (g16 == 0){
            if (k     < SLOTS) exw[(k    ) * 4 + h] = xa;
            if (k + 1 < SLOTS) exw[(k + 1) * 4 + h] = xb;
            if (k + 2 < SLOTS) exw[(k + 2) * 4 + h] = xc;
            if (k + 3 < SLOTS) exw[(k + 3) * 4 + h] = xd;
        }
    }
    for (; i < end; i++, k++){
        unsigned r0 = (unsigned)(s64[i] >> 32);
        uint4 u0 = *(const uint4*)(fs + (size_t)r0 * 512 + loff);
        float xa = __builtin_amdgcn_exp2f(rsum16(logit_p(u0, fd2, ar2)));
        den += xa;
        if (g16 == 0 && k < SLOTS) exw[k * 4 + h] = xa;
    }
    const float invden = __builtin_amdgcn_rcpf(den + 1e-16f);

    // ---- pass 2: ex from LDS, write att once, msg softmax, g ---------------
    f32x2 acc2[4];
    #pragma unroll
    for (int q = 0; q < 4; q++) acc2[q] = (f32x2){0.f, 0.f};

    const int deg = end - beg;
    const int nc  = deg < SLOTS ? deg : SLOTS;   // cached count

    i = beg; k = 0;
    for (; k + 2 <= nc; i += 2, k += 2){
        unsigned long long p0 = s64[i], p1 = s64[i + 1];
        unsigned lo0 = (unsigned)p0, lo1 = (unsigned)p1;
        unsigned sa0 = (unsigned)(p0 >> 32), sa1 = (unsigned)(p1 >> 32);
        int e0 = (int)(lo0 >> 5), e1 = (int)(lo1 >> 5);
        int rt0 = (int)(lo0 & 31), rt1 = (int)(lo1 & 31);

        uint4 ua = *(const uint4*)(fs + (size_t)sa0 * 512 + loff);
        uint4 ub = *(const uint4*)(fs + (size_t)sa1 * 512 + loff);
        float4 ra0 = *(const float4*)(rel + rt0 * 128 + d0);
        float4 ra1 = *(const float4*)(rel + rt0 * 128 + d0 + 4);
        float4 rb0 = *(const float4*)(rel + rt1 * 128 + d0);
        float4 rb1 = *(const float4*)(rel + rt1 * 128 + d0 + 4);

        float aa = exw[(k    ) * 4 + h] * invden;
        float ab = exw[(k + 1) * 4 + h] * invden;
        if (g16 == 0){
            att_out[(size_t)e0 * 4 + h] = aa;
            att_out[(size_t)e1 * 4 + h] = ab;
        }
        float sca = aa * LOG2E, scb = ab * LOG2E;

        f32x2 rra[4] = {{ra0.x, ra0.y}, {ra0.z, ra0.w}, {ra1.x, ra1.y}, {ra1.z, ra1.w}};
        f32x2 rrb[4] = {{rb0.x, rb0.y}, {rb0.z, rb0.w}, {rb1.x, rb1.y}, {rb1.z, rb1.w}};
        #pragma unroll
        for (int q = 0; q < 4; q++){ rra[q] *= sca; rrb[q] *= scb; }

        f32x2 eva[4], evb[4];
        f32x2 ssa = msg8(ua, rra, eva);
        f32x2 ssb = msg8(ub, rrb, evb);
        float sA = rsum16(ssa.x + ssa.y);
        float sB = rsum16(ssb.x + ssb.y);
        float iA = __builtin_amdgcn_rcpf(sA);
        float iB = __builtin_amdgcn_rcpf(sB);
        f32x2 iA2 = (f32x2){iA, iA}, iB2 = (f32x2){iB, iB};
        #pragma unroll
        for (int q = 0; q < 4; q++){
            acc2[q] = __builtin_elementwise_fma(eva[q], iA2, acc2[q]);
            acc2[q] = __builtin_elementwise_fma(evb[q], iB2, acc2[q]);
        }
    }
    for (; k < nc; i++, k++){
        unsigned long long p0 = s64[i];
        unsigned lo0 = (unsigned)p0;
        unsigned sa0 = (unsigned)(p0 >> 32);
        int e0 = (int)(lo0 >> 5);
        int rt0 = (int)(lo0 & 31);
        uint4 ua = *(const uint4*)(fs + (size_t)sa0 * 512 + loff);
        float4 ra0 = *(const float4*)(rel + rt0 * 128 + d0);
        float4 ra1 = *(const float4*)(rel + rt0 * 128 + d0 + 4);
        float aa = exw[k * 4 + h] * invden;
        if (g16 == 0) att_out[(size_t)e0 * 4 + h] = aa;
        float sca = aa * LOG2E;
        f32x2 rra[4] = {{ra0.x, ra0.y}, {ra0.z, ra0.w}, {ra1.x, ra1.y}, {ra1.z, ra1.w}};
        #pragma unroll
        for (int q = 0; q < 4; q++) rra[q] *= sca;
        f32x2 eva[4];
        f32x2 ssa = msg8(ua, rra, eva);
        float sA = rsum16(ssa.x + ssa.y);
        float iA = __builtin_amdgcn_rcpf(sA);
        f32x2 iA2 = (f32x2){iA, iA};
        #pragma unroll
        for (int q = 0; q < 4; q++)
            acc2[q] = __builtin_elementwise_fma(eva[q], iA2, acc2[q]);
    }
    // cold fallback: degree > SLOTS -> recompute logit for uncached edges
    for (; i < end; i++){
        unsigned long long p0 = s64[i];
        unsigned lo0 = (unsigned)p0;
        unsigned sa0 = (unsigned)(p0 >> 32);
        int e0 = (int)(lo0 >> 5);
        int rt0 = (int)(lo0 & 31);
        uint4 ua = *(const uint4*)(fs + (size_t)sa0 * 512 + loff);
        float4 ra0 = *(const float4*)(rel + rt0 * 128 + d0);
        float4 ra1 = *(const float4*)(rel + rt0 * 128 + d0 + 4);
        float pa = rsum16(logit_p(ua, fd2, ar2));
        float aa = __builtin_amdgcn_exp2f(pa) * invden;
        if (g16 == 0) att_out[(size_t)e0 * 4 + h] = aa;
        float sca = aa * LOG2E;
        f32x2 rra[4] = {{ra0.x, ra0.y}, {ra0.z, ra0.w}, {ra1.x, ra1.y}, {ra1.z, ra1.w}};
        #pragma unroll
        for (int q = 0; q < 4; q++) rra[q] *= sca;
        f32x2 eva[4];
        f32x2 ssa = msg8(ua, rra, eva);
        float sA = rsum16(ssa.x + ssa.y);
        float iA = __builtin_amdgcn_rcpf(sA);
        f32x2 iA2 = (f32x2){iA, iA};
        #pragma unroll
        for (int q = 0; q < 4; q++)
            acc2[q] = __builtin_elementwise_fma(eva[q], iA2, acc2[q]);
    }

    // sum the 4 head groups (cross-row: keep shfl, only 16 ops per dst)
    float accs[8];
    #pragma unroll
    for (int q = 0; q < 4; q++){ accs[2*q] = acc2[q].x; accs[2*q+1] = acc2[q].y; }
    #pragma unroll
    for (int j = 0; j < 8; j++){
        accs[j] += __shfl_xor(accs[j], 16);
        accs[j] += __shfl_xor(accs[j], 32);
    }
    if (lane < 16){
        float4 o0 = make_float4(accs[0], accs[1], accs[2], accs[3]);
        float4 o1 = make_float4(accs[4], accs[5], accs[6], accs[7]);
        *(float4*)(gout + (size_t)dt * 128 + d0)     = o0;
        *(float4*)(gout + (size_t)dt * 128 + d0 + 4) = o1;
    }
}

// ---------------- K6: final SIMT GEMM ---------------------------------------
__global__ __launch_bounds__(256)
void final_gemm(const float* __restrict__ node_emb,
                const int* __restrict__ ids,
                const float* __restrict__ gbuf,
                const float* __restrict__ W1,
                const float* __restrict__ b1,
                float* __restrict__ xout,
                float* __restrict__ embcat,
                int M)
{
    __shared__ float Alds[64][132];
    const int t = threadIdx.x;
    const int row0 = blockIdx.x * 64;

    #pragma unroll
    for (int i = 0; i < 8; i++){
        int j = t + i * 256;
        int r = j >> 5;
        int c4 = j & 31;
        int row = row0 + r;
        if (row > M - 1) row = M - 1;
        int nid = ids[row];
        float4 v  = ((const float4*)(node_emb + (size_t)nid * 128))[c4];
        float4 gv = ((const float4*)(gbuf + (size_t)row * 128))[c4];
        v.x += gv.x; v.y += gv.y; v.z += gv.z; v.w += gv.w;
        *(float4*)&Alds[r][c4 * 4] = v;
    }
    __syncthreads();

    const int tr = t >> 4;
    const int tc = t & 15;
    const int colbase = tc * 8;
    float acc[4][8];
    #pragma unroll
    for (int i = 0; i < 4; i++)
        #pragma unroll
        for (int j = 0; j < 8; j++) acc[i][j] = 0.f;

    const float* Wp = W1 + colbase;
    #pragma unroll 4
    for (int k = 0; k < 128; k += 4){
        float4 a0 = *(const float4*)&Alds[tr*4+0][k];
        float4 a1 = *(const float4*)&Alds[tr*4+1][k];
        float4 a2 = *(const float4*)&Alds[tr*4+2][k];
        float4 a3 = *(const float4*)&Alds[tr*4+3][k];
        #pragma unroll
        for (int kk = 0; kk < 4; kk++){
            float4 b0  = *(const float4*)(Wp + (k + kk) * 128);
            float4 b1v = *(const float4*)(Wp + (k + kk) * 128 + 4);
            float bb[8] = {b0.x,b0.y,b0.z,b0.w,b1v.x,b1v.y,b1v.z,b1v.w};
            float av[4] = { ((const float*)&a0)[kk], ((const float*)&a1)[kk],
                            ((const float*)&a2)[kk], ((const float*)&a3)[kk] };
            #pragma unroll
            for (int i = 0; i < 4; i++)
                #pragma unroll
                for (int j = 0; j < 8; j++)
                    acc[i][j] = fmaf(av[i], bb[j], acc[i][j]);
        }
    }

    float bs[8];
    #pragma unroll
    for (int j = 0; j < 8; j++) bs[j] = b1[colbase + j];
    #pragma unroll
    for (int i = 0; i < 4; i++){
        int row = row0 + tr * 4 + i;
        if (row < M){
            float o[8];
            #pragma unroll
            for (int j = 0; j < 8; j++){
                float y = acc[i][j] + bs[j];
                o[j] = fmaxf(y, 0.01f * y);
            }
            float4 o0 = make_float4(o[0], o[1], o[2], o[3]);
            float4 o1 = make_float4(o[4], o[5], o[6], o[7]);
            *(float4*)(xout   + (size_t)row * 128 + colbase)     = o0;
            *(float4*)(xout   + (size_t)row * 128 + colbase + 4) = o1;
            *(float4*)(embcat + (size_t)row * 128 + colbase)     = o0;
            *(float4*)(embcat + (size_t)row * 128 + colbase + 4) = o1;
        }
    }
}

extern "C" void kernel_launch(void* const* d_in, const int* in_sizes, int n_in,
                              void* d_out, int out_size, void* d_ws, size_t ws_size,
                              hipStream_t stream)
{
    const int*   src_ids    = (const int*)d_in[0];
    const int*   edge_src   = (const int*)d_in[1];
    const int*   edge_dst   = (const int*)d_in[2];
    const int*   edge_rtype = (const int*)d_in[3];
    const float* node_emb   = (const float*)d_in[4];
    const float* rel_emb    = (const float*)d_in[5];
    const float* w1_w       = (const float*)d_in[6];
    const float* w1_b       = (const float*)d_in[7];
    const float* w2s_w      = (const float*)d_in[8];
    const float* w2s_b      = (const float*)d_in[9];
    const float* w2d_w      = (const float*)d_in[10];
    const float* w2d_b      = (const float*)d_in[11];
    const float* attn       = (const float*)d_in[12];
    const int E = in_sizes[1];             // 3,200,000

    float* out      = (float*)d_out;
    float* x_out    = out;                          // 50000*128
    float* emb_cat  = out + (size_t)6400000;        // 50000*128
    float* g_out    = out + (size_t)12800000;       // 50000*128
    float* att_out  = out + (size_t)19200000;       // E*4

    char* ws = (char*)d_ws;
    unsigned short* feat_src = (unsigned short*)ws;                       // 102,400,000 B
    unsigned short* feat_dst = (unsigned short*)(ws + 102400000);         //  51,200,000 B
    int*  cnt    = (int*)(ws + 153600000);                                //     200,000 B
    int*  start  = (int*)(ws + 153800000);                                //     200,004 B
    int*  cursor = (int*)(ws + 154000008);                                //     200,000 B
    unsigned short* w2s_t = (unsigned short*)(ws + 154200008);            //     131,072 B
    unsigned short* w2d_t = (unsigned short*)(ws + 154331080);            //     131,072 B

    // sorted-edge uint64 array aliases the x_out output region:
    // E*8 = 25,600,000 B == 50000*128*4 B exactly. Written by K4, read by K5,
    // then x_out fully overwritten by K6 (same stream ordering).
    unsigned long long* s64 = (unsigned long long*)out;

    hipMemsetAsync(cnt, 0, NBINS * sizeof(int), stream);

    dim3 b256(256);
    transpose_w<<<256, b256, 0, stream>>>(w2s_w, w2s_t);
    transpose_w<<<256, b256, 0, stream>>>(w2d_w, w2d_t);
    feat_gemm_mfma<<<(NN_NODES + 63) / 64, b256, 0, stream>>>(
        node_emb, src_ids, w2s_t, w2s_b, feat_src, NN_NODES);
    feat_gemm_mfma<<<(NN_DST + 63) / 64, b256, 0, stream>>>(
        node_emb, src_ids, w2d_t, w2d_b, feat_dst, NN_DST);
    hist_kernel<<<(E + 255) / 256, b256, 0, stream>>>(edge_dst, cnt, E);
    scan_kernel<<<1, 1024, 0, stream>>>(cnt, start, cursor);
    scatter_kernel<<<(E + 255) / 256, b256, 0, stream>>>(
        edge_dst, edge_rtype, edge_src, cursor, s64, E);
    fused_edge<<<(NN_DST + 3) / 4, b256, 0, stream>>>(
        feat_src, feat_dst, rel_emb, s64, start, attn, att_out, g_out);
    final_gemm<<<(NN_DST + 63) / 64, b256, 0, stream>>>(
        node_emb, src_ids, g_out, w1_w, w1_b, x_out, emb_cat, NN_DST);
}